// Round 1
// baseline (474.395 us; speedup 1.0000x reference)
//
#include <hip/hip_runtime.h>

#define AS1 __attribute__((address_space(1)))
#define AS3 __attribute__((address_space(3)))

typedef __bf16 bf16;
typedef __bf16 bf16x8 __attribute__((ext_vector_type(8)));
typedef float f32x4 __attribute__((ext_vector_type(4)));

__device__ __forceinline__ void gld_lds16(const bf16* g, bf16* l) {
    __builtin_amdgcn_global_load_lds((const AS1 void*)g, (AS3 void*)l, 16, 0, 0);
}

// ---------------- fp32 -> bf16 cast ----------------
__global__ void cvt4_kernel(const float4* __restrict__ in, ushort4* __restrict__ out, int n4) {
    const int i = blockIdx.x * 256 + threadIdx.x;
    if (i >= n4) return;
    const float4 v = in[i];
    ushort4 r;
    r.x = __builtin_bit_cast(unsigned short, (bf16)v.x);
    r.y = __builtin_bit_cast(unsigned short, (bf16)v.y);
    r.z = __builtin_bit_cast(unsigned short, (bf16)v.z);
    r.w = __builtin_bit_cast(unsigned short, (bf16)v.w);
    out[i] = r;
}

// ---------------- GEMM: C[M,N] = A[M,K] * W[N,K]^T (both row-major, K contiguous) ----------------
// 128x128 tile, BK=64, 256 threads (4 waves in 2x2), mfma 16x16x32 bf16.
template <bool OUTF32>
__global__ void gemm_bt_kernel(const bf16* __restrict__ A, const bf16* __restrict__ W,
                               void* __restrict__ Cout, int M, int N, int K) {
    __shared__ __align__(16) bf16 lds[2 * 128 * 64];   // A tile [128][64], then B tile [128][64]
    const int tn = blockIdx.x * 128;
    const int tm = blockIdx.y * 128;
    const int tid = threadIdx.x;
    const int wave = tid >> 6;
    const int lane = tid & 63;
    const int wm = (wave >> 1) * 64;
    const int wn = (wave & 1) * 64;
    const int laneR = lane & 15;
    const int laneK = (lane >> 4) * 8;

    f32x4 acc[4][4] = {};

    for (int k0 = 0; k0 < K; k0 += 64) {
        // stage 32KB: 8 issues/wave x 64 lanes x 16B
#pragma unroll
        for (int iss = 0; iss < 8; ++iss) {
            const int Lb = iss * 4096 + wave * 1024;   // wave-uniform LDS byte base
            const int off = Lb + lane * 16;
            const bf16* g;
            if (off < 16384) {                 // A region: row stride 128B (64 bf16)
                const int row = off >> 7;
                const int cb = off & 127;
                g = A + (size_t)(tm + row) * K + (k0 + (cb >> 1));
            } else {                           // B region
                const int o2 = off - 16384;
                const int row = o2 >> 7;
                const int cb = o2 & 127;
                g = W + (size_t)(tn + row) * K + (k0 + (cb >> 1));
            }
            gld_lds16(g, (bf16*)((char*)lds + Lb));
        }
        __syncthreads();

        const bf16* ldsA = lds;
        const bf16* ldsB = lds + 128 * 64;
#pragma unroll
        for (int ks = 0; ks < 2; ++ks) {
            bf16x8 af[4], bfr[4];
#pragma unroll
            for (int i = 0; i < 4; ++i) {
                af[i]  = *(const bf16x8*)(ldsA + (wm + i * 16 + laneR) * 64 + ks * 32 + laneK);
                bfr[i] = *(const bf16x8*)(ldsB + (wn + i * 16 + laneR) * 64 + ks * 32 + laneK);
            }
#pragma unroll
            for (int i = 0; i < 4; ++i)
#pragma unroll
                for (int j = 0; j < 4; ++j)
                    acc[i][j] = __builtin_amdgcn_mfma_f32_16x16x32_bf16(af[i], bfr[j], acc[i][j], 0, 0, 0);
        }
        __syncthreads();
    }

    // epilogue: C/D layout col=lane&15, row=(lane>>4)*4+r
    const int rbase = (lane >> 4) * 4;
#pragma unroll
    for (int i = 0; i < 4; ++i) {
#pragma unroll
        for (int j = 0; j < 4; ++j) {
#pragma unroll
            for (int r = 0; r < 4; ++r) {
                const size_t row = (size_t)tm + wm + i * 16 + rbase + r;
                const size_t col = (size_t)tn + wn + j * 16 + laneR;
                if (OUTF32) ((float*)Cout)[row * N + col] = acc[i][j][r];
                else        ((bf16*)Cout)[row * N + col] = (bf16)acc[i][j][r];
            }
        }
    }
}

// ---------------- RoPE on q (pre-scaled by D^-0.5) and k; layout -> [h][s][d] ----------------
// C_qkv [2048][6144] bf16: cols 0..4095 q, 4096..5119 k, 5120..6143 v
__global__ void rope_qk_kernel(const bf16* __restrict__ C, bf16* __restrict__ Qr, bf16* __restrict__ Kr) {
    const int idx = blockIdx.x * 256 + threadIdx.x;
    const int NQ = 2048 * 32 * 64;
    const float SC = 0.08838834764831845f;         // 1/sqrt(128)
    const float LN1E4_64 = 0.14391156831212787f;   // ln(10000)/64
    if (idx < NQ) {
        const int f = idx & 63;
        const int t = idx >> 6;
        const int h = t & 31;
        const int s = t >> 5;
        const float x1 = (float)C[(size_t)s * 6144 + h * 128 + f];
        const float x2 = (float)C[(size_t)s * 6144 + h * 128 + f + 64];
        const float th = s * expf(-LN1E4_64 * (float)f);
        const float cs = cosf(th), sn = sinf(th);
        bf16* dst = Qr + ((size_t)h * 2048 + s) * 128 + f;
        dst[0]  = (bf16)((x1 * cs - x2 * sn) * SC);
        dst[64] = (bf16)((x2 * cs + x1 * sn) * SC);
    } else {
        const int i2 = idx - NQ;
        const int f = i2 & 63;
        const int t = i2 >> 6;
        const int h = t & 7;
        const int s = t >> 3;
        const float x1 = (float)C[(size_t)s * 6144 + 4096 + h * 128 + f];
        const float x2 = (float)C[(size_t)s * 6144 + 4096 + h * 128 + f + 64];
        const float th = s * expf(-LN1E4_64 * (float)f);
        const float cs = cosf(th), sn = sinf(th);
        bf16* dst = Kr + ((size_t)h * 2048 + s) * 128 + f;
        dst[0]  = (bf16)(x1 * cs - x2 * sn);
        dst[64] = (bf16)(x2 * cs + x1 * sn);
    }
}

// ---------------- V transpose: C_qkv v-cols -> Vt[hkv][d=128][s=2048] ----------------
__global__ void transpose_v_kernel(const bf16* __restrict__ C, bf16* __restrict__ Vt) {
    __shared__ __align__(16) unsigned short t[64][136];
    const int hkv = blockIdx.x >> 5;
    const int st = blockIdx.x & 31;
    const int s0 = st * 64;
    const int tid = threadIdx.x;
#pragma unroll
    for (int it = 0; it < 4; ++it) {
        const int l = it * 2048 + tid * 8;   // elem index in [64][128]
        const int r = l >> 7, c = l & 127;
        *(bf16x8*)&t[r][c] = *(const bf16x8*)&C[(size_t)(s0 + r) * 6144 + 5120 + hkv * 128 + c];
    }
    __syncthreads();
#pragma unroll
    for (int it = 0; it < 8; ++it) {
        const int o = it * 1024 + tid * 4;   // out elem index in [128 d][64 s]
        const int d = o >> 6, j = o & 63;
        ushort4 pk;
        pk.x = t[j + 0][d];
        pk.y = t[j + 1][d];
        pk.z = t[j + 2][d];
        pk.w = t[j + 3][d];
        *(ushort4*)&Vt[((size_t)hkv * 128 + d) * 2048 + s0 + j] = pk;
    }
}

// ---------------- causal GQA flash attention ----------------
// 1 block = (head h, 128 q rows). 4 waves x 32 q rows each. KV tile = 128.
// LDS: Klds [key][d] 32KB + Vlds [d][key] 32KB; P aliases Klds after a barrier.
__launch_bounds__(256, 2)
__global__ void flash_attn_kernel(const bf16* __restrict__ Qr, const bf16* __restrict__ Kr,
                                  const bf16* __restrict__ Vt, bf16* __restrict__ Aout) {
    __shared__ __align__(16) bf16 Klds[128 * 128];
    __shared__ __align__(16) bf16 Vlds[128 * 128];
    const int bid = blockIdx.x;
    const int h = bid & 31;
    const int i16 = bid >> 5;
    const int qb = (i16 < 8) ? (15 - i16) : (i16 - 8);   // heavy/light pairing across CUs
    const int hkv = h >> 2;                               // GROUPS=4
    const int q0 = qb * 128;
    const int tid = threadIdx.x;
    const int wave = tid >> 6, lane = tid & 63;
    const int laneR = lane & 15;
    const int laneK = (lane >> 4) * 8;
    const int rbase = (lane >> 4) * 4;

    // Q fragments in registers (already scaled by 1/sqrt(D))
    bf16x8 qf[2][4];
#pragma unroll
    for (int mi = 0; mi < 2; ++mi)
#pragma unroll
        for (int kc = 0; kc < 4; ++kc)
            qf[mi][kc] = *(const bf16x8*)&Qr[((size_t)h * 2048 + q0 + wave * 32 + mi * 16 + laneR) * 128 + kc * 32 + laneK];

    f32x4 o[2][8] = {};
    float mrow[2][4], lrow[2][4];
#pragma unroll
    for (int mi = 0; mi < 2; ++mi)
#pragma unroll
        for (int r = 0; r < 4; ++r) { mrow[mi][r] = -1e30f; lrow[mi][r] = 0.f; }

    const int ntiles = qb + 1;
    for (int t = 0; t < ntiles; ++t) {
        const int kv0 = t * 128;
        // stage K tile and V tile (each 32KB, linear)
#pragma unroll
        for (int iss = 0; iss < 8; ++iss) {
            const int Lb = iss * 4096 + wave * 1024;
            const int off = Lb + lane * 16;
            const int row = off >> 8;       // 256B per LDS row
            const int cb = off & 255;
            gld_lds16(&Kr[((size_t)hkv * 2048 + kv0 + row) * 128 + (cb >> 1)], (bf16*)((char*)Klds + Lb));
            gld_lds16(&Vt[((size_t)hkv * 128 + row) * 2048 + kv0 + (cb >> 1)], (bf16*)((char*)Vlds + Lb));
        }
        __syncthreads();

        // scores = Q K^T  (pre-scaled)
        f32x4 sc[2][8] = {};
#pragma unroll
        for (int kc = 0; kc < 4; ++kc) {
            bf16x8 kf[8];
#pragma unroll
            for (int j = 0; j < 8; ++j)
                kf[j] = *(const bf16x8*)&Klds[(j * 16 + laneR) * 128 + kc * 32 + laneK];
#pragma unroll
            for (int mi = 0; mi < 2; ++mi)
#pragma unroll
                for (int j = 0; j < 8; ++j)
                    sc[mi][j] = __builtin_amdgcn_mfma_f32_16x16x32_bf16(qf[mi][kc], kf[j], sc[mi][j], 0, 0, 0);
        }

        if (t == qb) {  // diagonal tile: causal mask
#pragma unroll
            for (int mi = 0; mi < 2; ++mi)
#pragma unroll
                for (int j = 0; j < 8; ++j)
#pragma unroll
                    for (int r = 0; r < 4; ++r) {
                        const int qr = wave * 32 + mi * 16 + rbase + r;
                        const int kr = j * 16 + laneR;
                        if (kr > qr) sc[mi][j][r] = -1e30f;
                    }
        }

        // online softmax (row lives in 16 lanes of a quad; reduce via shfl_xor 1/2/4/8)
#pragma unroll
        for (int mi = 0; mi < 2; ++mi) {
#pragma unroll
            for (int r = 0; r < 4; ++r) {
                float v = sc[mi][0][r];
#pragma unroll
                for (int j = 1; j < 8; ++j) v = fmaxf(v, sc[mi][j][r]);
                v = fmaxf(v, __shfl_xor(v, 1, 64));
                v = fmaxf(v, __shfl_xor(v, 2, 64));
                v = fmaxf(v, __shfl_xor(v, 4, 64));
                v = fmaxf(v, __shfl_xor(v, 8, 64));
                const float mnew = fmaxf(mrow[mi][r], v);
                const float fac = __expf(mrow[mi][r] - mnew);
                mrow[mi][r] = mnew;
                float rs = 0.f;
#pragma unroll
                for (int j = 0; j < 8; ++j) {
                    const float p = __expf(sc[mi][j][r] - mnew);
                    sc[mi][j][r] = p;
                    rs += p;
                }
                rs += __shfl_xor(rs, 1, 64);
                rs += __shfl_xor(rs, 2, 64);
                rs += __shfl_xor(rs, 4, 64);
                rs += __shfl_xor(rs, 8, 64);
                lrow[mi][r] = lrow[mi][r] * fac + rs;
#pragma unroll
                for (int j = 0; j < 8; ++j) o[mi][j][r] *= fac;
            }
        }

        __syncthreads();   // all waves done reading Klds -> safe to alias P into it

        // write P (bf16) into per-wave region of Klds
        bf16* Pw = Klds + wave * 32 * 128;
#pragma unroll
        for (int mi = 0; mi < 2; ++mi)
#pragma unroll
            for (int j = 0; j < 8; ++j)
#pragma unroll
                for (int r = 0; r < 4; ++r)
                    Pw[(mi * 16 + rbase + r) * 128 + j * 16 + laneR] = (bf16)sc[mi][j][r];

        // O += P V   (A-op = P from LDS, B-op = Vt rows, both key-contiguous)
#pragma unroll
        for (int kc = 0; kc < 4; ++kc) {
            bf16x8 pf[2], vf[8];
#pragma unroll
            for (int mi = 0; mi < 2; ++mi)
                pf[mi] = *(const bf16x8*)&Pw[(mi * 16 + laneR) * 128 + kc * 32 + laneK];
#pragma unroll
            for (int j = 0; j < 8; ++j)
                vf[j] = *(const bf16x8*)&Vlds[(j * 16 + laneR) * 128 + kc * 32 + laneK];
#pragma unroll
            for (int mi = 0; mi < 2; ++mi)
#pragma unroll
                for (int j = 0; j < 8; ++j)
                    o[mi][j] = __builtin_amdgcn_mfma_f32_16x16x32_bf16(pf[mi], vf[j], o[mi][j], 0, 0, 0);
        }
        __syncthreads();   // protect Klds/Vlds before next stage
    }

    // normalize + write attn output [s][h*128+d]
#pragma unroll
    for (int mi = 0; mi < 2; ++mi) {
        float rinv[4];
#pragma unroll
        for (int r = 0; r < 4; ++r) rinv[r] = 1.0f / lrow[mi][r];
#pragma unroll
        for (int j = 0; j < 8; ++j)
#pragma unroll
            for (int r = 0; r < 4; ++r) {
                const size_t row = (size_t)q0 + wave * 32 + mi * 16 + rbase + r;
                Aout[row * 4096 + h * 128 + j * 16 + laneR] = (bf16)(o[mi][j][r] * rinv[r]);
            }
    }
}

// ---------------- launch ----------------
extern "C" void kernel_launch(void* const* d_in, const int* in_sizes, int n_in,
                              void* d_out, int out_size, void* d_ws, size_t ws_size,
                              hipStream_t stream) {
    const float* hidden = (const float*)d_in[0];
    const float* Wq = (const float*)d_in[1];
    const float* Wk = (const float*)d_in[2];
    const float* Wv = (const float*)d_in[3];
    const float* Wo = (const float*)d_in[4];
    float* out = (float*)d_out;
    char* ws = (char*)d_ws;

    // workspace layout (bytes):
    bf16* hs = (bf16*)(ws + 0);                 // [2048][4096]        16 MiB
    bf16* Wb = (bf16*)(ws + 16777216);          // [10240][4096]       80 MiB (Wq|Wk|Wv|Wo)
    bf16* Cq = (bf16*)(ws + 100663296);         // [2048][6144]        24 MiB
    bf16* Qr = (bf16*)(ws + 125829120);         // [32][2048][128]     16 MiB
    bf16* Kr = (bf16*)(ws + 142606336);         // [8][2048][128]       4 MiB
    bf16* Vt = (bf16*)(ws + 146800640);         // [8][128][2048]       4 MiB
    bf16* At = (bf16*)(ws + 150994944);         // [2048][4096]        16 MiB
    (void)ws_size; (void)in_sizes; (void)n_in; (void)out_size;

    // 1. casts
    cvt4_kernel<<<8192, 256, 0, stream>>>((const float4*)hidden, (ushort4*)hs, 2097152);
    cvt4_kernel<<<16384, 256, 0, stream>>>((const float4*)Wq, (ushort4*)(Wb + 0), 4194304);
    cvt4_kernel<<<4096, 256, 0, stream>>>((const float4*)Wk, (ushort4*)(Wb + 16777216), 1048576);
    cvt4_kernel<<<4096, 256, 0, stream>>>((const float4*)Wv, (ushort4*)(Wb + 20971520), 1048576);
    cvt4_kernel<<<16384, 256, 0, stream>>>((const float4*)Wo, (ushort4*)(Wb + 25165824), 4194304);

    // 2. fused QKV projection: [2048,6144] = hs @ Wqkv^T
    gemm_bt_kernel<false><<<dim3(48, 16), 256, 0, stream>>>(hs, Wb, Cq, 2048, 6144, 4096);

    // 3. RoPE (+transpose to [h][s][d]); q pre-scaled by 1/sqrt(D)
    rope_qk_kernel<<<20480, 256, 0, stream>>>(Cq, Qr, Kr);

    // 4. V transpose -> [hkv][d][s]
    transpose_v_kernel<<<256, 256, 0, stream>>>(Cq, Vt);

    // 5. causal GQA flash attention -> At [2048][4096] bf16
    flash_attn_kernel<<<512, 256, 0, stream>>>(Qr, Kr, Vt, At);

    // 6. output projection: out = At @ Wo^T (fp32 out)
    gemm_bt_kernel<true><<<dim3(32, 16), 256, 0, stream>>>(At, Wb + 25165824, out, 2048, 4096, 4096);
}